// Round 4
// baseline (193.628 us; speedup 1.0000x reference)
//
#include <hip/hip_runtime.h>

#define BB 32
#define MM 512
#define NN 4096
#define KK 4
#define MLO 0.9999995f        // 1 - ~2^-21: conservative margin, no false negatives
#define FG_BITS 0x3F19999A    // bit pattern of 0.6f

// All IoU values are >= +0.0f, so float ordering == signed-int ordering on the
// bit patterns, with -1 (int) as a below-everything sentinel.

__device__ __forceinline__ float rfl_f(float x) {
    return __int_as_float(__builtin_amdgcn_readfirstlane(__float_as_int(x)));
}

struct T4 { int v0, v1, v2, v3; int i0, i1, i2, i3; float thr; };
struct B1 { int v; int i; float thr; };

// ---------------------------------------------------------------------------
// Kernel A: per-gt top-4 (exact JAX top_k tie-break) + max_per_gt; zero counts.
// One wave handles 4 gt rows; wave-shared (uniform) top-4 state per gt;
// mult-based trigger -> IEEE div only for candidate lanes; ballot+readlane
// merge in ascending proposal order.
// ---------------------------------------------------------------------------
__global__ __launch_bounds__(512) void kernA(const float* __restrict__ gt,
                                             const float* __restrict__ pr,
                                             float* __restrict__ maxpg,
                                             float* __restrict__ topv,
                                             int* __restrict__ topi,
                                             int* __restrict__ counts) {
    __shared__ float4 pbox[NN];            // 64 KB, xyxy
    const int b = blockIdx.x >> 4;         // 16 blocks per batch (512 gts / 32)
    const int mblk = blockIdx.x & 15;
    const int tid = threadIdx.x;

    const float4* p4 = (const float4*)(pr + (size_t)b * NN * 4);
    #pragma unroll
    for (int i = 0; i < NN / 512; ++i) {
        int n = i * 512 + tid;
        float4 q = p4[n];
        // 0.5*w is exact -> contraction-safe
        pbox[n] = make_float4(q.x - 0.5f * q.z, q.y - 0.5f * q.w,
                              q.x + 0.5f * q.z, q.y + 0.5f * q.w);
    }
    __syncthreads();

    const int wave = tid >> 6, lane = tid & 63;
    const int mbase = mblk * 32 + wave * 4;
    const float4* g4 = (const float4*)(gt + (size_t)b * MM * 4);

#define GTDEF(G) \
    float gx1_##G, gy1_##G, gx2_##G, gy2_##G, ga_##G; \
    { float4 gg = g4[mbase + G]; \
      float x1 = gg.x - 0.5f * gg.z, y1 = gg.y - 0.5f * gg.w; \
      float x2 = gg.x + 0.5f * gg.z, y2 = gg.y + 0.5f * gg.w; \
      gx1_##G = rfl_f(x1); gy1_##G = rfl_f(y1); \
      gx2_##G = rfl_f(x2); gy2_##G = rfl_f(y2); \
      ga_##G = rfl_f(__fmul_rn(x2 - x1, y2 - y1)); }

    GTDEF(0) GTDEF(1) GTDEF(2) GTDEF(3)

    T4 t0 = {-1, -1, -1, -1, 0, 0, 0, 0, 0.0f};
    T4 t1 = t0, t2 = t0, t3 = t0;

#define GTSTEP(T, G) \
    { float ltx = fmaxf(gx1_##G, q.x), lty = fmaxf(gy1_##G, q.y); \
      float rbx = fminf(gx2_##G, q.z), rby = fminf(gy2_##G, q.w); \
      float wc = fmaxf(rbx - ltx, 0.0f), hc = fmaxf(rby - lty, 0.0f); \
      float inter = __fmul_rn(wc, hc); \
      float un = (ga_##G + pa) - inter; \
      float u = fmaxf(un, 1e-9f); \
      bool trig; \
      if (T.v3 < 0) trig = true;                    /* slots not yet filled */ \
      else if (T.v3 == 0) trig = inter > 0.0f;      /* exact: iou>0 <=> inter>0 */ \
      else trig = inter >= T.thr * u;               /* conservative, no misses */ \
      float iouv = 0.0f; \
      if (trig) iouv = inter / u;                   /* exact IEEE, sparse */ \
      unsigned long long mk = __ballot(trig); \
      if (mk) { \
        do { \
          int l = __ffsll((unsigned long long)mk) - 1; mk &= mk - 1; \
          int vb = (int)__builtin_amdgcn_readlane(__float_as_int(iouv), l); \
          if (vb > T.v3) {                          /* strict: exact tie rule */ \
            int n = nb + l; \
            bool c2 = vb > T.v2, c1 = vb > T.v1, c0 = vb > T.v0; \
            T.v3 = c2 ? T.v2 : vb;               T.i3 = c2 ? T.i2 : n; \
            T.v2 = c2 ? (c1 ? T.v1 : vb) : T.v2; T.i2 = c2 ? (c1 ? T.i1 : n) : T.i2; \
            T.v1 = c1 ? (c0 ? T.v0 : vb) : T.v1; T.i1 = c1 ? (c0 ? T.i0 : n) : T.i1; \
            T.v0 = c0 ? vb : T.v0;               T.i0 = c0 ? n : T.i0; \
          } \
        } while (mk); \
        T.thr = (T.v3 <= 0) ? 0.0f : __int_as_float(T.v3) * MLO; \
      } }

    for (int j = 0; j < NN / 64; ++j) {
        float4 q = pbox[j * 64 + lane];
        float pa = __fmul_rn(q.z - q.x, q.w - q.y);
        const int nb = j * 64;
        GTSTEP(t0, 0)
        GTSTEP(t1, 1)
        GTSTEP(t2, 2)
        GTSTEP(t3, 3)
    }

    if (lane == 0) {
#define WOUT(T, G) \
        { int gm = b * MM + mbase + G; \
          maxpg[gm] = __int_as_float(T.v0); \
          topv[gm * KK + 0] = __int_as_float(T.v0); \
          topv[gm * KK + 1] = __int_as_float(T.v1); \
          topv[gm * KK + 2] = __int_as_float(T.v2); \
          topv[gm * KK + 3] = __int_as_float(T.v3); \
          topi[gm * KK + 0] = T.i0; topi[gm * KK + 1] = T.i1; \
          topi[gm * KK + 2] = T.i2; topi[gm * KK + 3] = T.i3; \
          counts[gm] = 0; }
        WOUT(t0, 0) WOUT(t1, 1) WOUT(t2, 2) WOUT(t3, 3)
    }
}

// ---------------------------------------------------------------------------
// Kernel B: per-proposal argmax over gts (first-max), fg/lq, count scatter.
// One wave handles 8 proposals; lanes span 64 gts per step; wave-shared
// argmax state; combined trigger covers both "beats best" and "equals
// per-gt max" (iou <= max_per_gt always, so one lower bound suffices).
// ---------------------------------------------------------------------------
__global__ __launch_bounds__(512) void kernB(const float* __restrict__ gt,
                                             const float* __restrict__ pr,
                                             const float* __restrict__ maxpg,
                                             int* __restrict__ counts) {
    __shared__ float4 gbox[MM];            // 8 KB, xyxy
    __shared__ float4 gaux[MM];            // 8 KB: {gar, gmx*MLO, gmx, 0}
    const int b = blockIdx.x >> 6;         // 64 blocks per batch (4096 / 64)
    const int nblk = blockIdx.x & 63;
    const int tid = threadIdx.x;

    {   int m = tid;                        // 512 threads == MM
        float4 gg = ((const float4*)(gt + (size_t)b * MM * 4))[m];
        float x1 = gg.x - 0.5f * gg.z, y1 = gg.y - 0.5f * gg.w;
        float x2 = gg.x + 0.5f * gg.z, y2 = gg.y + 0.5f * gg.w;
        gbox[m] = make_float4(x1, y1, x2, y2);
        float gmx = maxpg[b * MM + m];
        gaux[m] = make_float4(__fmul_rn(x2 - x1, y2 - y1), gmx * MLO, gmx, 0.0f);
    }
    __syncthreads();

    const int wave = tid >> 6, lane = tid & 63;
    const int pbase = nblk * 64 + wave * 8;
    const float4* p4 = (const float4*)(pr + (size_t)b * NN * 4);

#define PDEF(P) \
    float qx1_##P, qy1_##P, qx2_##P, qy2_##P, pa_##P; \
    { float4 qq = p4[pbase + P]; \
      float x1 = qq.x - 0.5f * qq.z, y1 = qq.y - 0.5f * qq.w; \
      float x2 = qq.x + 0.5f * qq.z, y2 = qq.y + 0.5f * qq.w; \
      qx1_##P = rfl_f(x1); qy1_##P = rfl_f(y1); \
      qx2_##P = rfl_f(x2); qy2_##P = rfl_f(y2); \
      pa_##P = rfl_f(__fmul_rn(x2 - x1, y2 - y1)); }

    PDEF(0) PDEF(1) PDEF(2) PDEF(3) PDEF(4) PDEF(5) PDEF(6) PDEF(7)

    // argmax init (0, idx 0) is exact: max>=0 always, and max==0 => all zero
    // => first achiever is m=0.
    B1 b0 = {0, 0, 0.0f}, b1 = b0, b2 = b0, b3 = b0;
    B1 b4 = b0, b5 = b0, b6 = b0, b7 = b0;
    int lqm = 0;                           // per-lane lq bits, one per proposal

#define PSTEP(BP, P) \
    { float ltx = fmaxf(qx1_##P, gb.x), lty = fmaxf(qy1_##P, gb.y); \
      float rbx = fminf(qx2_##P, gb.z), rby = fminf(qy2_##P, gb.w); \
      float wc = fmaxf(rbx - ltx, 0.0f), hc = fmaxf(rby - lty, 0.0f); \
      float inter = __fmul_rn(wc, hc); \
      float un = (ax.x + pa_##P) - inter; \
      float u = fmaxf(un, 1e-9f); \
      bool trig; \
      if (BP.v == 0) trig = (inter > 0.0f) || (ax.z == 0.0f); \
      else trig = inter >= fminf(BP.thr, ax.y) * u; \
      float iouv = 0.0f; \
      if (trig) { iouv = inter / u; \
                  if (iouv == ax.z) lqm |= (1 << P); }  /* exact lq equality */ \
      unsigned long long mk = __ballot(trig); \
      if (mk) { \
        do { int l = __ffsll((unsigned long long)mk) - 1; mk &= mk - 1; \
          int vb = (int)__builtin_amdgcn_readlane(__float_as_int(iouv), l); \
          if (vb > BP.v) { BP.v = vb; BP.i = mb + l; }  /* first-max wins */ \
        } while (mk); \
        BP.thr = (BP.v == 0) ? 0.0f : __int_as_float(BP.v) * MLO; \
      } }

    for (int s = 0; s < MM / 64; ++s) {
        const int mb = s * 64;
        float4 gb = gbox[mb + lane];
        float4 ax = gaux[mb + lane];
        PSTEP(b0, 0) PSTEP(b1, 1) PSTEP(b2, 2) PSTEP(b3, 3)
        PSTEP(b4, 4) PSTEP(b5, 5) PSTEP(b6, 6) PSTEP(b7, 7)
    }

    bool lq0 = __ballot(lqm & 1)   != 0ull, lq1 = __ballot(lqm & 2)   != 0ull;
    bool lq2 = __ballot(lqm & 4)   != 0ull, lq3 = __ballot(lqm & 8)   != 0ull;
    bool lq4 = __ballot(lqm & 16)  != 0ull, lq5 = __ballot(lqm & 32)  != 0ull;
    bool lq6 = __ballot(lqm & 64)  != 0ull, lq7 = __ballot(lqm & 128) != 0ull;

    if (lane == 0) {
        const int cb = b * MM;
        if ((b0.v >= FG_BITS) | lq0) atomicAdd(&counts[cb + b0.i], 1);
        if ((b1.v >= FG_BITS) | lq1) atomicAdd(&counts[cb + b1.i], 1);
        if ((b2.v >= FG_BITS) | lq2) atomicAdd(&counts[cb + b2.i], 1);
        if ((b3.v >= FG_BITS) | lq3) atomicAdd(&counts[cb + b3.i], 1);
        if ((b4.v >= FG_BITS) | lq4) atomicAdd(&counts[cb + b4.i], 1);
        if ((b5.v >= FG_BITS) | lq5) atomicAdd(&counts[cb + b5.i], 1);
        if ((b6.v >= FG_BITS) | lq6) atomicAdd(&counts[cb + b6.i], 1);
        if ((b7.v >= FG_BITS) | lq7) atomicAdd(&counts[cb + b7.i], 1);
    }
}

// ---------------------------------------------------------------------------
// Kernel C: write the 4 concatenated float32 output sections.
// ---------------------------------------------------------------------------
__global__ __launch_bounds__(256) void kernC(const float* __restrict__ topv,
                                             const int* __restrict__ topi,
                                             const int* __restrict__ counts,
                                             float* __restrict__ out) {
    const int gm = blockIdx.x * 256 + threadIdx.x;   // 0 .. B*M-1
    if (gm >= BB * MM) return;
    const int cnt = counts[gm];
    const int m = gm & (MM - 1);
    float* sc = out;
    float* pi = out + (size_t)BB * MM * KK;
    float* gi = out + (size_t)2 * BB * MM * KK;
    float* va = out + (size_t)3 * BB * MM * KK;
    #pragma unroll
    for (int k = 0; k < KK; ++k) {
        const bool val = k < cnt;
        sc[gm * KK + k] = val ? topv[gm * KK + k] : 0.0f;
        pi[gm * KK + k] = (float)topi[gm * KK + k];
        gi[gm * KK + k] = (float)m;
        va[gm * KK + k] = val ? 1.0f : 0.0f;
    }
}

extern "C" void kernel_launch(void* const* d_in, const int* in_sizes, int n_in,
                              void* d_out, int out_size, void* d_ws, size_t ws_size,
                              hipStream_t stream) {
    const float* gt = (const float*)d_in[0];   // [B,M,4] cxcywh
    const float* pr = (const float*)d_in[1];   // [B,N,4] cxcywh
    // d_in[2] (gt_labels) is unused by the reference outputs.
    float* out = (float*)d_out;
    char* ws = (char*)d_ws;

    int*   counts = (int*)(ws);                 //  64 KB
    float* maxpg  = (float*)(ws + (1 << 16));   //  64 KB
    float* topv   = (float*)(ws + (2 << 16));   // 256 KB
    int*   topi   = (int*)(ws + (6 << 16));     // 256 KB

    kernA<<<BB * (MM / 32), 512, 0, stream>>>(gt, pr, maxpg, topv, topi, counts);
    kernB<<<BB * (NN / 64), 512, 0, stream>>>(gt, pr, maxpg, counts);
    kernC<<<(BB * MM + 255) / 256, 256, 0, stream>>>(topv, topi, counts, out);
}

// Round 7
// 140.147 us; speedup vs baseline: 1.3816x; 1.3816x over previous
//
#include <hip/hip_runtime.h>

#define BB 32
#define MM 512
#define NN 4096
#define KK 4
#define IOU_T 0.6f
#define MLO 0.9999995f        // 1 - ~2^-21: conservative margin, no false negatives

// All IoU values are >= +0.0f, so float ordering == signed-int ordering on the
// bit patterns, with -1 (int) as a below-everything sentinel.

__device__ __forceinline__ float rfl_f(float x) {
    return __int_as_float(__builtin_amdgcn_readfirstlane(__float_as_int(x)));
}

struct T4 { int v0, v1, v2, v3; int i0, i1, i2, i3; float thr; };

// ---------------------------------------------------------------------------
// Kernel A: per-gt top-4 (exact JAX top_k tie-break) + max_per_gt; zero counts.
// One wave handles 4 gt rows, wave-shared (uniform) top-4 state per gt.
// Common path per element: 12 core ops + 2-op mult trigger, NO div, NO branch.
// All 4 gts' rare work (exact divs + ordered serial merges + thr refresh)
// deferred into ONE branch per 64-element iteration.
// Trigger uses previous-iteration thr: stale thr is smaller -> conservative.
//   thr = -1 : slots unfilled -> inter > -u always true (u >= 1e-9)
//   thr =  0 : zero-filled    -> inter > 0  <=> iou > 0 (exact)
//   thr = v3*MLO : margin covers div rounding; ties (==v3) correctly excluded
//                  since stored index is always smaller (insertion in n-order).
// ---------------------------------------------------------------------------
__global__ __launch_bounds__(512) void kernA(const float* __restrict__ gt,
                                             const float* __restrict__ pr,
                                             float* __restrict__ maxpg,
                                             float* __restrict__ topv,
                                             int* __restrict__ topi,
                                             int* __restrict__ counts) {
    __shared__ float4 pbox[NN];            // 64 KB, xyxy
    const int b = blockIdx.x >> 4;         // 16 blocks per batch (512 gts / 32)
    const int mblk = blockIdx.x & 15;
    const int tid = threadIdx.x;

    const float4* p4 = (const float4*)(pr + (size_t)b * NN * 4);
    #pragma unroll
    for (int i = 0; i < NN / 512; ++i) {
        int n = i * 512 + tid;
        float4 q = p4[n];
        // 0.5*w exact -> fma contraction harmless (identical rounding)
        pbox[n] = make_float4(q.x - 0.5f * q.z, q.y - 0.5f * q.w,
                              q.x + 0.5f * q.z, q.y + 0.5f * q.w);
    }
    __syncthreads();

    const int wave = tid >> 6, lane = tid & 63;
    const int mbase = mblk * 32 + wave * 4;
    const float4* g4 = (const float4*)(gt + (size_t)b * MM * 4);

#define GTDEF(G) \
    float gx1_##G, gy1_##G, gx2_##G, gy2_##G, ga_##G; \
    { float4 gg = g4[mbase + G]; \
      float x1 = gg.x - 0.5f * gg.z, y1 = gg.y - 0.5f * gg.w; \
      float x2 = gg.x + 0.5f * gg.z, y2 = gg.y + 0.5f * gg.w; \
      gx1_##G = rfl_f(x1); gy1_##G = rfl_f(y1); \
      gx2_##G = rfl_f(x2); gy2_##G = rfl_f(y2); \
      ga_##G = rfl_f(__fmul_rn(x2 - x1, y2 - y1)); }

    GTDEF(0) GTDEF(1) GTDEF(2) GTDEF(3)

    T4 t0 = {-1, -1, -1, -1, 0, 0, 0, 0, -1.0f};
    T4 t1 = t0, t2 = t0, t3 = t0;

    // Branchless common path: intersection + union + trigger only.
#define COMP(T, G, IN, UU, TR) \
    float IN, UU; bool TR; \
    { float ltx = fmaxf(gx1_##G, q.x), lty = fmaxf(gy1_##G, q.y); \
      float rbx = fminf(gx2_##G, q.z), rby = fminf(gy2_##G, q.w); \
      float wc = fmaxf(rbx - ltx, 0.0f), hc = fmaxf(rby - lty, 0.0f); \
      IN = __fmul_rn(wc, hc); \
      UU = fmaxf((ga_##G + pa) - IN, 1e-9f); \
      TR = IN > T.thr * UU; }

    // Rare path: exact IEEE div for triggered lanes, ordered serial merge.
#define MERGE(T, MK, IN, UU, TR) \
    if (MK) { \
      float iouv = 0.0f; \
      if (TR) iouv = IN / UU; \
      unsigned long long mk = MK; \
      do { \
        int l = __ffsll((unsigned long long)mk) - 1; mk &= mk - 1; \
        int vb = (int)__builtin_amdgcn_readlane(__float_as_int(iouv), l); \
        if (vb > T.v3) { \
          int n = nb + l; \
          bool c2 = vb > T.v2, c1 = vb > T.v1, c0 = vb > T.v0; \
          T.v3 = c2 ? T.v2 : vb;               T.i3 = c2 ? T.i2 : n; \
          T.v2 = c2 ? (c1 ? T.v1 : vb) : T.v2; T.i2 = c2 ? (c1 ? T.i1 : n) : T.i2; \
          T.v1 = c1 ? (c0 ? T.v0 : vb) : T.v1; T.i1 = c1 ? (c0 ? T.i0 : n) : T.i1; \
          T.v0 = c0 ? vb : T.v0;               T.i0 = c0 ? n : T.i0; \
        } \
      } while (mk); \
      T.thr = (T.v3 < 0) ? -1.0f \
            : ((T.v3 == 0) ? 0.0f : __int_as_float(T.v3) * MLO); \
    }

    for (int j = 0; j < NN / 64; ++j) {
        float4 q = pbox[j * 64 + lane];
        float pa = __fmul_rn(q.z - q.x, q.w - q.y);
        const int nb = j * 64;
        COMP(t0, 0, in0, uu0, tr0)
        COMP(t1, 1, in1, uu1, tr1)
        COMP(t2, 2, in2, uu2, tr2)
        COMP(t3, 3, in3, uu3, tr3)
        unsigned long long mk0 = __ballot(tr0), mk1 = __ballot(tr1);
        unsigned long long mk2 = __ballot(tr2), mk3 = __ballot(tr3);
        if ((mk0 | mk1) | (mk2 | mk3)) {    // single rare branch per iter
            MERGE(t0, mk0, in0, uu0, tr0)
            MERGE(t1, mk1, in1, uu1, tr1)
            MERGE(t2, mk2, in2, uu2, tr2)
            MERGE(t3, mk3, in3, uu3, tr3)
        }
    }

    if (lane == 0) {
#define WOUT(T, G) \
        { int gm = b * MM + mbase + G; \
          maxpg[gm] = __int_as_float(T.v0); \
          topv[gm * KK + 0] = __int_as_float(T.v0); \
          topv[gm * KK + 1] = __int_as_float(T.v1); \
          topv[gm * KK + 2] = __int_as_float(T.v2); \
          topv[gm * KK + 3] = __int_as_float(T.v3); \
          topi[gm * KK + 0] = T.i0; topi[gm * KK + 1] = T.i1; \
          topi[gm * KK + 2] = T.i2; topi[gm * KK + 3] = T.i3; \
          counts[gm] = 0; }
        WOUT(t0, 0) WOUT(t1, 1) WOUT(t2, 2) WOUT(t3, 3)
    }
}

// ---------------------------------------------------------------------------
// Kernel B: per-proposal argmax over gts (first-max), fg/lq, count scatter.
// Branchless, exact IEEE div per element (control overhead proved costlier
// than the div in round 4). Thread-per-proposal, full 512-gt loop,
// broadcast LDS reads (b128 + b64 per gt-step).
// ---------------------------------------------------------------------------
__global__ __launch_bounds__(256) void kernB(const float* __restrict__ gt,
                                             const float* __restrict__ pr,
                                             const float* __restrict__ maxpg,
                                             int* __restrict__ counts) {
    __shared__ float4 gbox[MM];            // xyxy, 8 KB
    __shared__ float2 gaux[MM];            // (area, gmx), 4 KB
    const int b = blockIdx.x >> 4;         // 16 blocks per batch (4096/256)
    const int nblk = blockIdx.x & 15;
    const int tid = threadIdx.x;

    for (int m = tid; m < MM; m += 256) {
        float4 gg = ((const float4*)(gt + (size_t)b * MM * 4))[m];
        float x1 = gg.x - 0.5f * gg.z, y1 = gg.y - 0.5f * gg.w;
        float x2 = gg.x + 0.5f * gg.z, y2 = gg.y + 0.5f * gg.w;
        gbox[m] = make_float4(x1, y1, x2, y2);
        gaux[m] = make_float2(__fmul_rn(x2 - x1, y2 - y1), maxpg[b * MM + m]);
    }
    __syncthreads();

    const int n = nblk * 256 + tid;
    float4 q = ((const float4*)(pr + (size_t)b * NN * 4))[n];
    const float qx1 = q.x - 0.5f * q.z, qy1 = q.y - 0.5f * q.w;
    const float qx2 = q.x + 0.5f * q.z, qy2 = q.y + 0.5f * q.w;
    const float pa = __fmul_rn(qx2 - qx1, qy2 - qy1);

    // init (0, idx 0) is exact: iou >= 0 always; all-zero row -> argmax = 0.
    float best = 0.0f;
    int bidx = 0;
    bool lq = false;
    #pragma unroll 8
    for (int m = 0; m < MM; ++m) {
        float4 gb = gbox[m];
        float2 ax = gaux[m];
        float ltx = fmaxf(gb.x, qx1), lty = fmaxf(gb.y, qy1);
        float rbx = fminf(gb.z, qx2), rby = fminf(gb.w, qy2);
        float w = fmaxf(rbx - ltx, 0.0f), h = fmaxf(rby - lty, 0.0f);
        float inter = __fmul_rn(w, h);
        float u = fmaxf((ax.x + pa) - inter, 1e-9f);
        float iou = inter / u;              // exact IEEE: rounded-tie semantics
        bool c = iou > best;                // first max kept, like jnp.argmax
        best = c ? iou : best;
        bidx = c ? m : bidx;
        lq = lq || (iou == ax.y);           // exact equality vs per-gt max
    }
    if (best >= IOU_T || lq) {
        atomicAdd(&counts[b * MM + bidx], 1);
    }
}

// ---------------------------------------------------------------------------
// Kernel C: write the 4 concatenated float32 output sections.
// ---------------------------------------------------------------------------
__global__ __launch_bounds__(256) void kernC(const float* __restrict__ topv,
                                             const int* __restrict__ topi,
                                             const int* __restrict__ counts,
                                             float* __restrict__ out) {
    const int gm = blockIdx.x * 256 + threadIdx.x;   // 0 .. B*M-1
    if (gm >= BB * MM) return;
    const int cnt = counts[gm];
    const int m = gm & (MM - 1);
    float* sc = out;
    float* pi = out + (size_t)BB * MM * KK;
    float* gi = out + (size_t)2 * BB * MM * KK;
    float* va = out + (size_t)3 * BB * MM * KK;
    #pragma unroll
    for (int k = 0; k < KK; ++k) {
        const bool val = k < cnt;
        sc[gm * KK + k] = val ? topv[gm * KK + k] : 0.0f;
        pi[gm * KK + k] = (float)topi[gm * KK + k];
        gi[gm * KK + k] = (float)m;
        va[gm * KK + k] = val ? 1.0f : 0.0f;
    }
}

extern "C" void kernel_launch(void* const* d_in, const int* in_sizes, int n_in,
                              void* d_out, int out_size, void* d_ws, size_t ws_size,
                              hipStream_t stream) {
    const float* gt = (const float*)d_in[0];   // [B,M,4] cxcywh
    const float* pr = (const float*)d_in[1];   // [B,N,4] cxcywh
    // d_in[2] (gt_labels) is unused by the reference outputs.
    float* out = (float*)d_out;
    char* ws = (char*)d_ws;

    int*   counts = (int*)(ws);                 //  64 KB
    float* maxpg  = (float*)(ws + (1 << 16));   //  64 KB
    float* topv   = (float*)(ws + (2 << 16));   // 256 KB
    int*   topi   = (int*)(ws + (6 << 16));     // 256 KB

    kernA<<<BB * (MM / 32), 512, 0, stream>>>(gt, pr, maxpg, topv, topi, counts);
    kernB<<<BB * (NN / 256), 256, 0, stream>>>(gt, pr, maxpg, counts);
    kernC<<<(BB * MM + 255) / 256, 256, 0, stream>>>(topv, topi, counts, out);
}

// Round 8
// 114.034 us; speedup vs baseline: 1.6980x; 1.2290x over previous
//
#include <hip/hip_runtime.h>

#define BB 32
#define MM 512
#define NN 4096
#define KK 4
#define MLO 0.9999995f        // 1 - ~2^-21: conservative margin, no false negatives
#define FG_BITS 0x3F19999A    // bit pattern of 0.6f

// All IoU values are >= +0.0f, so float ordering == signed-int ordering on the
// bit patterns, with -1 (int) as a below-everything sentinel.

__device__ __forceinline__ bool beatsI(int v1, int i1, int v2, int i2) {
    // total order: value descending, index ascending (JAX top_k tie-break)
    return (v1 > v2) || (v1 == v2 && i1 < i2);
}

// branchless compare-exchange keeping the winner in (av,ai)
#define CE(av, ai, bv, bi)                                        \
    {                                                             \
        bool _s = beatsI(bv, bi, av, ai);                         \
        int _mv = _s ? bv : av, _nv = _s ? av : bv;               \
        int _mi = _s ? bi : ai, _ni = _s ? ai : bi;               \
        av = _mv; bv = _nv; ai = _mi; bi = _ni;                   \
    }

struct T4 { int v0, v1, v2, v3; int i0, i1, i2, i3; float thr; };

// ---------------------------------------------------------------------------
// Kernel A: per-gt top-4 (exact JAX top_k tie-break) + max_per_gt; zero counts.
// One wave handles 4 gt rows, wave-shared (uniform) top-4 state per gt.
// j=0 PRIME: exact iou for 64 lanes + 6-step bitonic butterfly -> top-4,
// replacing the 64-candidate serial merge that serialized round 7 (43% VALU).
// j>0: branchless common path (~14 ops/pair), ONE combined ballot; rare
// merges (exact div + ordered serial insert + thr refresh) behind one branch.
//   thr = 0     : v3==0 -> trigger inter>0  <=> iou>0 (exact)
//   thr = v3*MLO: margin covers div rounding; ties (==v3) correctly excluded
//                 since stored index is always smaller (insertion in n-order).
// ---------------------------------------------------------------------------
__global__ __launch_bounds__(512) void kernA(const float* __restrict__ gt,
                                             const float* __restrict__ pr,
                                             float* __restrict__ maxpg,
                                             float* __restrict__ topv,
                                             int* __restrict__ topi,
                                             int* __restrict__ counts) {
    __shared__ float4 pbox[NN];            // 64 KB, xyxy
    const int b = blockIdx.x >> 4;         // 16 blocks per batch (512 gts / 32)
    const int mblk = blockIdx.x & 15;
    const int tid = threadIdx.x;

    const float4* p4 = (const float4*)(pr + (size_t)b * NN * 4);
    #pragma unroll
    for (int i = 0; i < NN / 512; ++i) {
        int n = i * 512 + tid;
        float4 q = p4[n];
        // 0.5*w exact -> fma contraction harmless (identical rounding)
        pbox[n] = make_float4(q.x - 0.5f * q.z, q.y - 0.5f * q.w,
                              q.x + 0.5f * q.z, q.y + 0.5f * q.w);
    }
    __syncthreads();

    const int wave = tid >> 6, lane = tid & 63;
    const int mbase = mblk * 32 + wave * 4;
    const float4* g4 = (const float4*)(gt + (size_t)b * MM * 4);

#define GTDEF(G) \
    float gx1_##G, gy1_##G, gx2_##G, gy2_##G, ga_##G; \
    { float4 gg = g4[mbase + G]; \
      float x1 = gg.x - 0.5f * gg.z, y1 = gg.y - 0.5f * gg.w; \
      float x2 = gg.x + 0.5f * gg.z, y2 = gg.y + 0.5f * gg.w; \
      gx1_##G = x1; gy1_##G = y1; gx2_##G = x2; gy2_##G = y2; \
      ga_##G = __fmul_rn(x2 - x1, y2 - y1); }

    GTDEF(0) GTDEF(1) GTDEF(2) GTDEF(3)

    T4 t0, t1, t2, t3;

    // ---- PRIME (j = 0): exact iou all lanes, butterfly -> uniform top-4 ----
#define PIOU(G, VB) \
    int VB; \
    { float ltx = fmaxf(gx1_##G, q.x), lty = fmaxf(gy1_##G, q.y); \
      float rbx = fminf(gx2_##G, q.z), rby = fminf(gy2_##G, q.w); \
      float wc = fmaxf(rbx - ltx, 0.0f), hc = fmaxf(rby - lty, 0.0f); \
      float inter = __fmul_rn(wc, hc); \
      float u = fmaxf((ga_##G + pa) - inter, 1e-9f); \
      VB = __float_as_int(inter / u); }

#define PRIME(T, VB) \
    { int x0 = VB, x1 = -1, x2 = -1, x3 = -1; \
      int y0 = lane, y1 = 0x7fffffff, y2 = 0x7fffffff, y3 = 0x7fffffff; \
      for (int off = 1; off < 64; off <<= 1) { \
        int b0 = __shfl_xor(x0, off), b1 = __shfl_xor(x1, off); \
        int b2 = __shfl_xor(x2, off), b3 = __shfl_xor(x3, off); \
        int j0 = __shfl_xor(y0, off), j1 = __shfl_xor(y1, off); \
        int j2 = __shfl_xor(y2, off), j3 = __shfl_xor(y3, off); \
        /* z = [x0..x3, b3..b0] bitonic (desc then asc) */ \
        int z4 = b3, z5 = b2, z6 = b1, z7 = b0; \
        int w4 = j3, w5 = j2, w6 = j1, w7 = j0; \
        CE(x0, y0, z4, w4); CE(x1, y1, z5, w5); \
        CE(x2, y2, z6, w6); CE(x3, y3, z7, w7); \
        CE(x0, y0, x2, y2); CE(x1, y1, x3, y3); \
        CE(x0, y0, x1, y1); CE(x2, y2, x3, y3); \
      } \
      T.v0 = x0; T.v1 = x1; T.v2 = x2; T.v3 = x3; \
      T.i0 = y0; T.i1 = y1; T.i2 = y2; T.i3 = y3; \
      T.thr = (T.v3 <= 0) ? 0.0f : __int_as_float(T.v3) * MLO; }

    {
        float4 q = pbox[lane];
        float pa = __fmul_rn(q.z - q.x, q.w - q.y);
        PIOU(0, vb0) PIOU(1, vb1) PIOU(2, vb2) PIOU(3, vb3)
        PRIME(t0, vb0) PRIME(t1, vb1) PRIME(t2, vb2) PRIME(t3, vb3)
    }

    // ---- STREAM (j = 1..63): branchless common path, sparse rare merges ----
#define COMP(T, G, IN, UU, TR) \
    float IN, UU; bool TR; \
    { float ltx = fmaxf(gx1_##G, q.x), lty = fmaxf(gy1_##G, q.y); \
      float rbx = fminf(gx2_##G, q.z), rby = fminf(gy2_##G, q.w); \
      float wc = fmaxf(rbx - ltx, 0.0f), hc = fmaxf(rby - lty, 0.0f); \
      IN = __fmul_rn(wc, hc); \
      UU = fmaxf((ga_##G + pa) - IN, 1e-9f); \
      TR = IN > T.thr * UU; }

#define MERGE(T, MK, IN, UU, TR) \
    if (MK) { \
      float iouv = 0.0f; \
      if (TR) iouv = IN / UU; \
      unsigned long long mk = MK; \
      do { \
        int l = __ffsll((unsigned long long)mk) - 1; mk &= mk - 1; \
        int vb = (int)__builtin_amdgcn_readlane(__float_as_int(iouv), l); \
        if (vb > T.v3) { \
          int n = nb + l; \
          bool c2 = vb > T.v2, c1 = vb > T.v1, c0 = vb > T.v0; \
          T.v3 = c2 ? T.v2 : vb;               T.i3 = c2 ? T.i2 : n; \
          T.v2 = c2 ? (c1 ? T.v1 : vb) : T.v2; T.i2 = c2 ? (c1 ? T.i1 : n) : T.i2; \
          T.v1 = c1 ? (c0 ? T.v0 : vb) : T.v1; T.i1 = c1 ? (c0 ? T.i0 : n) : T.i1; \
          T.v0 = c0 ? vb : T.v0;               T.i0 = c0 ? n : T.i0; \
        } \
      } while (mk); \
      T.thr = (T.v3 == 0) ? 0.0f : __int_as_float(T.v3) * MLO; \
    }

    for (int j = 1; j < NN / 64; ++j) {
        float4 q = pbox[j * 64 + lane];
        float pa = __fmul_rn(q.z - q.x, q.w - q.y);
        const int nb = j * 64;
        COMP(t0, 0, in0, uu0, tr0)
        COMP(t1, 1, in1, uu1, tr1)
        COMP(t2, 2, in2, uu2, tr2)
        COMP(t3, 3, in3, uu3, tr3)
        if (__ballot((tr0 | tr1) | (tr2 | tr3))) {   // single combined ballot
            unsigned long long mk0 = __ballot(tr0), mk1 = __ballot(tr1);
            unsigned long long mk2 = __ballot(tr2), mk3 = __ballot(tr3);
            MERGE(t0, mk0, in0, uu0, tr0)
            MERGE(t1, mk1, in1, uu1, tr1)
            MERGE(t2, mk2, in2, uu2, tr2)
            MERGE(t3, mk3, in3, uu3, tr3)
        }
    }

    if (lane == 0) {
#define WOUT(T, G) \
        { int gm = b * MM + mbase + G; \
          maxpg[gm] = __int_as_float(T.v0); \
          topv[gm * KK + 0] = __int_as_float(T.v0); \
          topv[gm * KK + 1] = __int_as_float(T.v1); \
          topv[gm * KK + 2] = __int_as_float(T.v2); \
          topv[gm * KK + 3] = __int_as_float(T.v3); \
          topi[gm * KK + 0] = T.i0; topi[gm * KK + 1] = T.i1; \
          topi[gm * KK + 2] = T.i2; topi[gm * KK + 3] = T.i3; \
          counts[gm] = 0; }
        WOUT(t0, 0) WOUT(t1, 1) WOUT(t2, 2) WOUT(t3, 3)
    }
}

// ---------------------------------------------------------------------------
// Kernel B: per-proposal argmax over gts (first-max), fg/lq, count scatter.
// Branchless exact IEEE div per element. 64 proposals per 256-thread block;
// wave q reduces gt quarter [128q,128q+128); partials merged in LDS in
// quarter order with strict > (preserves jnp.argmax first-max semantics).
// Grid 2048 blocks -> 8 blocks/CU (round 7 had 512 -> 25% occupancy).
// ---------------------------------------------------------------------------
__global__ __launch_bounds__(256) void kernB(const float* __restrict__ gt,
                                             const float* __restrict__ pr,
                                             const float* __restrict__ maxpg,
                                             int* __restrict__ counts) {
    __shared__ float4 gbox[MM];            // xyxy, 8 KB
    __shared__ float2 gaux[MM];            // (area, gmx), 4 KB
    __shared__ int sV[256], sI[256], sL[256];   // 3 KB
    const int b = blockIdx.x >> 6;         // 64 blocks per batch (4096/64)
    const int nblk = blockIdx.x & 63;
    const int tid = threadIdx.x;

    for (int m = tid; m < MM; m += 256) {
        float4 gg = ((const float4*)(gt + (size_t)b * MM * 4))[m];
        float x1 = gg.x - 0.5f * gg.z, y1 = gg.y - 0.5f * gg.w;
        float x2 = gg.x + 0.5f * gg.z, y2 = gg.y + 0.5f * gg.w;
        gbox[m] = make_float4(x1, y1, x2, y2);
        gaux[m] = make_float2(__fmul_rn(x2 - x1, y2 - y1), maxpg[b * MM + m]);
    }
    __syncthreads();

    const int p = tid & 63;                // proposal within group
    const int qtr = tid >> 6;              // gt quarter == wave id
    const int n = nblk * 64 + p;
    float4 qq = ((const float4*)(pr + (size_t)b * NN * 4))[n];
    const float qx1 = qq.x - 0.5f * qq.z, qy1 = qq.y - 0.5f * qq.w;
    const float qx2 = qq.x + 0.5f * qq.z, qy2 = qq.y + 0.5f * qq.w;
    const float pa = __fmul_rn(qx2 - qx1, qy2 - qy1);

    // per-quarter init (0, first m of quarter) merges to the exact global
    // argmax: strict > in quarter order keeps the first achiever.
    const int m0 = qtr * (MM / 4);
    float best = 0.0f;
    int bidx = m0;
    bool lq = false;
    #pragma unroll 4
    for (int mm = 0; mm < MM / 4; ++mm) {
        const int m = m0 + mm;
        float4 gb = gbox[m];
        float2 ax = gaux[m];
        float ltx = fmaxf(gb.x, qx1), lty = fmaxf(gb.y, qy1);
        float rbx = fminf(gb.z, qx2), rby = fminf(gb.w, qy2);
        float w = fmaxf(rbx - ltx, 0.0f), h = fmaxf(rby - lty, 0.0f);
        float inter = __fmul_rn(w, h);
        float u = fmaxf((ax.x + pa) - inter, 1e-9f);
        float iou = inter / u;              // exact IEEE: rounded-tie semantics
        bool c = iou > best;                // first max kept, like jnp.argmax
        best = c ? iou : best;
        bidx = c ? m : bidx;
        lq = lq || (iou == ax.y);           // exact equality vs per-gt max
    }
    sV[tid] = __float_as_int(best);
    sI[tid] = bidx;
    sL[tid] = lq ? 1 : 0;
    __syncthreads();

    if (tid < 64) {
        int v = sV[tid], i = sI[tid], L = sL[tid];
        #pragma unroll
        for (int q2 = 1; q2 < 4; ++q2) {
            int v2 = sV[tid + q2 * 64], i2 = sI[tid + q2 * 64];
            L |= sL[tid + q2 * 64];
            bool c = v2 > v;               // strict: lower quarter wins ties
            v = c ? v2 : v;
            i = c ? i2 : i;
        }
        if (v >= FG_BITS || L) {           // int cmp == float cmp (non-neg)
            atomicAdd(&counts[b * MM + i], 1);
        }
    }
}

// ---------------------------------------------------------------------------
// Kernel C: write the 4 concatenated float32 output sections.
// ---------------------------------------------------------------------------
__global__ __launch_bounds__(256) void kernC(const float* __restrict__ topv,
                                             const int* __restrict__ topi,
                                             const int* __restrict__ counts,
                                             float* __restrict__ out) {
    const int gm = blockIdx.x * 256 + threadIdx.x;   // 0 .. B*M-1
    if (gm >= BB * MM) return;
    const int cnt = counts[gm];
    const int m = gm & (MM - 1);
    float* sc = out;
    float* pi = out + (size_t)BB * MM * KK;
    float* gi = out + (size_t)2 * BB * MM * KK;
    float* va = out + (size_t)3 * BB * MM * KK;
    #pragma unroll
    for (int k = 0; k < KK; ++k) {
        const bool val = k < cnt;
        sc[gm * KK + k] = val ? topv[gm * KK + k] : 0.0f;
        pi[gm * KK + k] = (float)topi[gm * KK + k];
        gi[gm * KK + k] = (float)m;
        va[gm * KK + k] = val ? 1.0f : 0.0f;
    }
}

extern "C" void kernel_launch(void* const* d_in, const int* in_sizes, int n_in,
                              void* d_out, int out_size, void* d_ws, size_t ws_size,
                              hipStream_t stream) {
    const float* gt = (const float*)d_in[0];   // [B,M,4] cxcywh
    const float* pr = (const float*)d_in[1];   // [B,N,4] cxcywh
    // d_in[2] (gt_labels) is unused by the reference outputs.
    float* out = (float*)d_out;
    char* ws = (char*)d_ws;

    int*   counts = (int*)(ws);                 //  64 KB
    float* maxpg  = (float*)(ws + (1 << 16));   //  64 KB
    float* topv   = (float*)(ws + (2 << 16));   // 256 KB
    int*   topi   = (int*)(ws + (6 << 16));     // 256 KB

    kernA<<<BB * (MM / 32), 512, 0, stream>>>(gt, pr, maxpg, topv, topi, counts);
    kernB<<<BB * (NN / 64), 256, 0, stream>>>(gt, pr, maxpg, counts);
    kernC<<<(BB * MM + 255) / 256, 256, 0, stream>>>(topv, topi, counts, out);
}